// Round 2
// baseline (414.556 us; speedup 1.0000x reference)
//
#include <hip/hip_runtime.h>

// SPA (second-price auction) payment kernel.
// x: (BATCH, 16) fp32. Per row: top-2 (m1, m2). out[j] = (x[j]==m1 ? m2 : m1), clamp >= 0.
// Tie semantics: if >=2 elements equal m1 then m2==m1, so the elementwise form matches
// the reference's first-argmax form exactly.
//
// Layout: 4 lanes per row, one float4 per lane (16B/lane, fully coalesced).
// Each thread processes TWO independent quads (tid and tid+half) to double
// memory-level parallelism per thread and halve wave count.
// Nontemporal load/store: data is touched exactly once — skip cache allocation.

typedef float f32x4 __attribute__((ext_vector_type(4)));

__device__ __forceinline__ void top2_quad(f32x4 v, float& m1, float& m2) {
    float a = fmaxf(v.x, v.y), b = fminf(v.x, v.y);
    float c = fmaxf(v.z, v.w), d = fminf(v.z, v.w);
    m1 = fmaxf(a, c);
    m2 = fmaxf(fminf(a, c), fmaxf(b, d));
}

__device__ __forceinline__ f32x4 payment(f32x4 v, float m1, float m2) {
    f32x4 o;
    o.x = fmaxf((v.x == m1) ? m2 : m1, 0.0f);
    o.y = fmaxf((v.y == m1) ? m2 : m1, 0.0f);
    o.z = fmaxf((v.z == m1) ? m2 : m1, 0.0f);
    o.w = fmaxf((v.w == m1) ? m2 : m1, 0.0f);
    return o;
}

__global__ __launch_bounds__(256) void _SpaPayment_88399016886488_kernel(
    const f32x4* __restrict__ x, f32x4* __restrict__ out, int half) {
    int tid = blockIdx.x * blockDim.x + threadIdx.x;
    if (tid >= half) return;

    // two independent streams, both coalesced (consecutive lanes -> consecutive quads)
    f32x4 v0 = __builtin_nontemporal_load(x + tid);
    f32x4 v1 = __builtin_nontemporal_load(x + tid + half);

    float a1, a2, b1, b2;
    top2_quad(v0, a1, a2);
    top2_quad(v1, b1, b2);

    // merge (m1,m2) across the 4 lanes of each row; both streams interleaved
    // (rows are 4 consecutive lanes; half is divisible by 4 so stream 1 rows align too)
    #pragma unroll
    for (int off = 1; off <= 2; off <<= 1) {
        float oa1 = __shfl_xor(a1, off);
        float oa2 = __shfl_xor(a2, off);
        float ob1 = __shfl_xor(b1, off);
        float ob2 = __shfl_xor(b2, off);
        float hia = fmaxf(a1, oa1), loa = fminf(a1, oa1);
        a1 = hia;
        a2 = fmaxf(loa, fmaxf(a2, oa2));
        float hib = fmaxf(b1, ob1), lob = fminf(b1, ob1);
        b1 = hib;
        b2 = fmaxf(lob, fmaxf(b2, ob2));
    }

    __builtin_nontemporal_store(payment(v0, a1, a2), out + tid);
    __builtin_nontemporal_store(payment(v1, b1, b2), out + tid + half);
}

extern "C" void kernel_launch(void* const* d_in, const int* in_sizes, int n_in,
                              void* d_out, int out_size, void* d_ws, size_t ws_size,
                              hipStream_t stream) {
    const f32x4* x = (const f32x4*)d_in[0];
    f32x4* out = (f32x4*)d_out;
    int n = in_sizes[0];          // 4194304 * 16 elements
    int nquads = n / 4;           // 16777216 float4s
    int half = nquads / 2;        // 8388608 threads, 2 quads each
    int block = 256;
    int grid = (half + block - 1) / block;   // 32768 blocks (exact)
    _SpaPayment_88399016886488_kernel<<<grid, block, 0, stream>>>(x, out, half);
}